// Round 9
// baseline (153.241 us; speedup 1.0000x reference)
//
#include <hip/hip_runtime.h>

#define C_DIM 1024
#define N_DIM 1024
#define O_DIM 2048
#define K_NN  20
#define KCAT  3072  // 3 * 1024: [Whi,Whi,Wlo] x [hhi,hlo,hhi]
#define NZ    4     // dist GEMM split-K factor (round-2-validated partition)

typedef __attribute__((ext_vector_type(8))) short bf16x8;
typedef __attribute__((ext_vector_type(4))) float f32x4;

__device__ __forceinline__ unsigned short f2bf(float f) {
  unsigned u = __float_as_uint(f);
  unsigned r = (u + 0x7fffu + ((u >> 16) & 1u)) >> 16;  // RNE
  return (unsigned short)r;
}
__device__ __forceinline__ float bf2f(unsigned short h) {
  return __uint_as_float((unsigned)h << 16);
}

#define GLOAD16(gp, lp)                                                       \
  __builtin_amdgcn_global_load_lds(                                           \
      (const __attribute__((address_space(1))) unsigned int*)(uintptr_t)(gp), \
      (__attribute__((address_space(3))) unsigned int*)(uintptr_t)(lp), 16,   \
      0, 0)

// ---------------------------------------------------------------------------
// PREP (role-split, one launch): blocks [0,1024) transpose x/eps -> xT,gT;
// [1024,2048) conv W -> Acat; [2048,2304) norms partials (fp64).
// ---------------------------------------------------------------------------
__global__ __launch_bounds__(256) void prep_kernel(
    const float* __restrict__ x, const float* __restrict__ eps,
    const float* __restrict__ W, float* __restrict__ xT,
    float* __restrict__ gT, unsigned short* __restrict__ Acat,
    double* __restrict__ part) {
  int b = blockIdx.x;
  int t = threadIdx.x;
  if (b < 1024) {
    __shared__ float tx_[32][33], tg_[32][33];
    int bx = (b & 31) * 32, by = (b >> 5) * 32;
    int c = t & 31, r = t >> 5;
#pragma unroll
    for (int rr = 0; rr < 4; ++rr) {
      int row = by + r + 8 * rr;
      float xv = x[(size_t)row * N_DIM + bx + c];
      float ev = eps[(size_t)row * N_DIM + bx + c];
      tx_[r + 8 * rr][c] = xv;
      tg_[r + 8 * rr][c] = (1.f + ev) * xv;
    }
    __syncthreads();
#pragma unroll
    for (int rr = 0; rr < 4; ++rr) {
      xT[(size_t)(bx + r + 8 * rr) * C_DIM + by + c] = tx_[c][r + 8 * rr];
      gT[(size_t)(bx + r + 8 * rr) * C_DIM + by + c] = tg_[c][r + 8 * rr];
    }
  } else if (b < 2048) {
    int id = (b - 1024) * 256 + t;
    int m = id >> 7;
    int gh = id & 127;
    int g = gh >> 2, h = gh & 3;
    int c1 = g * 32 + h * 4;
    const float* wp = &W[(size_t)m * C_DIM];
    float4 v1 = *(const float4*)&wp[c1];
    float4 v2 = *(const float4*)&wp[c1 + 16];
    float vv[8] = {v1.x, v1.y, v1.z, v1.w, v2.x, v2.y, v2.z, v2.w};
    unsigned hi[8], lo[8];
#pragma unroll
    for (int i = 0; i < 8; ++i) {
      unsigned short hb = f2bf(vv[i]);
      hi[i] = hb;
      lo[i] = f2bf(vv[i] - bf2f(hb));
    }
    uint4 ph, pl;
    ph.x = hi[0] | (hi[1] << 16); ph.y = hi[2] | (hi[3] << 16);
    ph.z = hi[4] | (hi[5] << 16); ph.w = hi[6] | (hi[7] << 16);
    pl.x = lo[0] | (lo[1] << 16); pl.y = lo[2] | (lo[3] << 16);
    pl.z = lo[4] | (lo[5] << 16); pl.w = lo[6] | (lo[7] << 16);
    int s = g >> 1;
    int pc = ((g & 1) * 4 + h) ^ (m & 7);
    unsigned short* row = Acat + (size_t)m * KCAT;
    *(uint4*)(row + s * 64 + pc * 8) = ph;
    *(uint4*)(row + 1024 + s * 64 + pc * 8) = ph;
    *(uint4*)(row + 2048 + s * 64 + pc * 8) = pl;
  } else {
    int b2 = b - 2048;
    int j = (b2 & 3) * 256 + t;
    int cb = b2 >> 2;  // 0..63
    double acc = 0.0;
    int c0 = cb * 16;
#pragma unroll
    for (int c = c0; c < c0 + 16; ++c) {
      float v = x[(size_t)c * N_DIM + j];
      acc = fma((double)v, (double)v, acc);
    }
    part[(size_t)cb * N_DIM + j] = acc;
  }
}

// ---------------------------------------------------------------------------
// DIST: blocks [0,1024) = fp32 sym split-K=4 GEMM (KZ=256, BK=32, register
// prefetch before compute), [1024,1028) = norms reduce. Per-thread FMA order
// = ascending k over 256 -> identical to the round-2-validated partition.
// ---------------------------------------------------------------------------
__global__ __launch_bounds__(256) void dist_kernel(
    const float* __restrict__ A, float* __restrict__ P,
    const double* __restrict__ part, double* __restrict__ s_d) {
  int b = blockIdx.x;
  int t = threadIdx.x;
  if (b >= 1024) {
    int j = (b - 1024) * 256 + t;
    double a = 0.0;
#pragma unroll
    for (int cb = 0; cb < 64; ++cb) a += part[(size_t)cb * N_DIM + j];
    s_d[j] = a;
    return;
  }
  const int KZ = 256;
  int z = b >> 8;
  int bx = (b >> 4) & 15, by = b & 15;
  if (by > bx) return;  // upper triangle only (uniform early return)
  __shared__ float Al[32][64];
  __shared__ float Bl[32][64];
  int tx = t & 15, ty = t >> 4;
  int m0 = by * 64, n0 = bx * 64;
  int kk = t >> 4, c4 = (t & 15) * 4;
  float acc[4][4] = {};
  int k0 = z * KZ;
  float4 a0 = *(const float4*)&A[(size_t)(k0 + kk) * N_DIM + m0 + c4];
  float4 a1 = *(const float4*)&A[(size_t)(k0 + kk + 16) * N_DIM + m0 + c4];
  float4 b0 = *(const float4*)&A[(size_t)(k0 + kk) * N_DIM + n0 + c4];
  float4 b1 = *(const float4*)&A[(size_t)(k0 + kk + 16) * N_DIM + n0 + c4];
  for (int kt = 0; kt < KZ / 32; ++kt) {
    __syncthreads();
    *(float4*)&Al[kk][c4] = a0;
    *(float4*)&Al[kk + 16][c4] = a1;
    *(float4*)&Bl[kk][c4] = b0;
    *(float4*)&Bl[kk + 16][c4] = b1;
    __syncthreads();
    if (kt + 1 < KZ / 32) {
      int kn = k0 + (kt + 1) * 32;
      a0 = *(const float4*)&A[(size_t)(kn + kk) * N_DIM + m0 + c4];
      a1 = *(const float4*)&A[(size_t)(kn + kk + 16) * N_DIM + m0 + c4];
      b0 = *(const float4*)&A[(size_t)(kn + kk) * N_DIM + n0 + c4];
      b1 = *(const float4*)&A[(size_t)(kn + kk + 16) * N_DIM + n0 + c4];
    }
#pragma unroll
    for (int q = 0; q < 32; ++q) {
      float4 a = *(const float4*)&Al[q][ty * 4];
      float4 bq = *(const float4*)&Bl[q][tx * 4];
      float am[4] = {a.x, a.y, a.z, a.w};
      float bn[4] = {bq.x, bq.y, bq.z, bq.w};
#pragma unroll
      for (int i = 0; i < 4; ++i)
#pragma unroll
        for (int j = 0; j < 4; ++j)
          acc[i][j] = fmaf(am[i], bn[j], acc[i][j]);
    }
  }
#pragma unroll
  for (int i = 0; i < 4; ++i) {
    float4 v = make_float4(acc[i][0], acc[i][1], acc[i][2], acc[i][3]);
    *(float4*)&P[((size_t)z * N_DIM + m0 + ty * 4 + i) * N_DIM + n0 + tx * 4] = v;
  }
  if (bx != by) {  // mirror (products commutative -> bitwise identical)
#pragma unroll
    for (int j = 0; j < 4; ++j) {
      float4 v = make_float4(acc[0][j], acc[1][j], acc[2][j], acc[3][j]);
      *(float4*)&P[((size_t)z * N_DIM + n0 + tx * 4 + j) * N_DIM + m0 + ty * 4] = v;
    }
  }
}

// ---------------------------------------------------------------------------
// TOPK + GATHER fused (NZ=4 combine; otherwise unchanged).
// ---------------------------------------------------------------------------
__global__ __launch_bounds__(128) void topk_gather_kernel(
    const float* __restrict__ P, const double* __restrict__ s_d,
    const float* __restrict__ xT, const float* __restrict__ gT,
    unsigned short* __restrict__ Bcat) {
  __shared__ int sidx[K_NN];
  int i = blockIdx.x;
  int t = threadIdx.x;
  if (t < 64) {
    int l = t;
    double d[16];
#pragma unroll
    for (int q = 0; q < 16; ++q) {
      int j = q * 64 + l;
      double s = 0.0;
#pragma unroll
      for (int z = 0; z < NZ; ++z)
        s += (double)P[((size_t)z * N_DIM + i) * N_DIM + j];
      d[q] = 2.0 * s - s_d[j];
    }
    for (int r = 0; r < K_NN; ++r) {
      double bv = -1e300;
      int bj = N_DIM;
#pragma unroll
      for (int q = 0; q < 16; ++q) {
        int j = q * 64 + l;
        if (d[q] > bv) { bv = d[q]; bj = j; }
      }
#pragma unroll
      for (int off = 32; off; off >>= 1) {
        double ov = __shfl_xor(bv, off);
        int oj = __shfl_xor(bj, off);
        if (ov > bv || (ov == bv && oj < bj)) { bv = ov; bj = oj; }
      }
      if (l == 0) sidx[r] = bj;
      int kq = bj >> 6, kl = bj & 63;
      if (l == kl) {
#pragma unroll
        for (int q = 0; q < 16; ++q)
          if (q == kq) d[q] = -1e300;
      }
    }
  }
  __syncthreads();
  int n = i;
  int g = t >> 2, h = t & 3;
  int c1 = g * 32 + h * 4;
  int nb[K_NN];
#pragma unroll
  for (int k = 0; k < K_NN; ++k) nb[k] = sidx[k];
  float4 s1 = *(const float4*)&gT[(size_t)n * C_DIM + c1];
  float4 s2 = *(const float4*)&gT[(size_t)n * C_DIM + c1 + 16];
#pragma unroll
  for (int k = 0; k < K_NN; ++k) {
    const float* rp = &xT[(size_t)nb[k] * C_DIM];
    float4 v1 = *(const float4*)&rp[c1];
    float4 v2 = *(const float4*)&rp[c1 + 16];
    s1.x += v1.x; s1.y += v1.y; s1.z += v1.z; s1.w += v1.w;
    s2.x += v2.x; s2.y += v2.y; s2.z += v2.z; s2.w += v2.w;
  }
  float vv[8] = {s1.x, s1.y, s1.z, s1.w, s2.x, s2.y, s2.z, s2.w};
  unsigned hi[8], lo[8];
#pragma unroll
  for (int i2 = 0; i2 < 8; ++i2) {
    unsigned short hb = f2bf(vv[i2]);
    hi[i2] = hb;
    lo[i2] = f2bf(vv[i2] - bf2f(hb));
  }
  uint4 ph, pl;
  ph.x = hi[0] | (hi[1] << 16); ph.y = hi[2] | (hi[3] << 16);
  ph.z = hi[4] | (hi[5] << 16); ph.w = hi[6] | (hi[7] << 16);
  pl.x = lo[0] | (lo[1] << 16); pl.y = lo[2] | (lo[3] << 16);
  pl.z = lo[4] | (lo[5] << 16); pl.w = lo[6] | (lo[7] << 16);
  int s = g >> 1;
  int pc = ((g & 1) * 4 + h) ^ (n & 7);
  unsigned short* row = Bcat + (size_t)n * KCAT;
  *(uint4*)(row + s * 64 + pc * 8) = ph;
  *(uint4*)(row + 1024 + s * 64 + pc * 8) = pl;
  *(uint4*)(row + 2048 + s * 64 + pc * 8) = ph;
}

// ---------------------------------------------------------------------------
// bf16 MFMA GEMM: out (2048x1024) = Acat x Bcat^T. 128x128 tile, grid 128,
// ONE n-panel per XCD (bx = b&7): B-panel 768KB L2-resident, A read once per
// XCD (L3 traffic ~102MB vs round-8's ~288MB). 8 waves = 4m x 2n, wave tile
// 32x64 (2m x 4n frags). 3 LDS bufs (96KB), 2-ahead prefetch, vmcnt(4).
// Each acc chain stays k-ascending -> bitwise-identical to round 8.
// ---------------------------------------------------------------------------
__global__ __launch_bounds__(512) void mfma_gemm(
    const unsigned short* __restrict__ Acat,
    const unsigned short* __restrict__ Bcat, float* __restrict__ out) {
  __shared__ unsigned short Alds[3][8192];  // 3 x 16KB (128 rows x 64 k)
  __shared__ unsigned short Blds[3][8192];  // 3 x 16KB (128 rows x 64 k)
  int t = threadIdx.x;
  int w = t >> 6, l = t & 63;
  int b = blockIdx.x;
  int bx = b & 7;   // n-tile == XCD (8 tiles of 128)
  int by = b >> 3;  // m-tile (16 tiles of 128)
  int m0 = by * 128, n0 = bx * 128;
  int wr = w >> 1, wc = w & 1;
  int h = l >> 4, c16 = l & 15;
  int s8 = c16 & 7;

  // staging: A/B each 128 rows x 8 chunks = 1024 chunks; thread t does
  // chunks t and t+512 of each (rows t>>3 and 64+(t>>3), chunk t&7).
  const char* gA = (const char*)Acat + (size_t)(m0 + (t >> 3)) * (KCAT * 2) +
                   (t & 7) * 16;
  const char* gB = (const char*)Bcat + (size_t)(n0 + (t >> 3)) * (KCAT * 2) +
                   (t & 7) * 16;

  // frag LDS offsets (ushort units): row*64 + ((4*wk+h)^s8)*8
#define AOFF(mi, wk) ((wr * 32 + (mi)*16 + c16) * 64 + ((((wk)*4 + h) ^ s8) * 8))
#define BOFF(nj, wk) ((wc * 64 + (nj)*16 + c16) * 64 + ((((wk)*4 + h) ^ s8) * 8))

  f32x4 acc[2][4] = {};

#define STAGE3(bufi, itv)                                                 \
  {                                                                       \
    const char* ga = gA + (size_t)(itv) * 128;                            \
    const char* gb = gB + (size_t)(itv) * 128;                            \
    GLOAD16(ga, (char*)&Alds[bufi][0] + t * 16);                          \
    GLOAD16(ga + (size_t)64 * (KCAT * 2),                                 \
            (char*)&Alds[bufi][0] + 8192 + t * 16);                       \
    GLOAD16(gb, (char*)&Blds[bufi][0] + t * 16);                          \
    GLOAD16(gb + (size_t)64 * (KCAT * 2),                                 \
            (char*)&Blds[bufi][0] + 8192 + t * 16);                       \
  }

#define COMPUTE(bufi)                                                          \
  {                                                                            \
    const unsigned short* Ab = &Alds[bufi][0];                                 \
    const unsigned short* Bb = &Blds[bufi][0];                                 \
    _Pragma("unroll") for (int wk = 0; wk < 2; ++wk) {                         \
      bf16x8 af0 = *(const bf16x8*)(Ab + AOFF(0, wk));                         \
      bf16x8 af1 = *(const bf16x8*)(Ab + AOFF(1, wk));                         \
      bf16x8 bf0 = *(const bf16x8*)(Bb + BOFF(0, wk));                         \
      bf16x8 bf1 = *(const bf16x8*)(Bb + BOFF(1, wk));                         \
      bf16x8 bf2 = *(const bf16x8*)(Bb + BOFF(2, wk));                         \
      bf16x8 bf3 = *(const bf16x8*)(Bb + BOFF(3, wk));                         \
      acc[0][0] = __builtin_amdgcn_mfma_f32_16x16x32_bf16(af0, bf0, acc[0][0], 0, 0, 0); \
      acc[0][1] = __builtin_amdgcn_mfma_f32_16x16x32_bf16(af0, bf1, acc[0][1], 0, 0, 0); \
      acc[0][2] = __builtin_amdgcn_mfma_f32_16x16x32_bf16(af0, bf2, acc[0][2], 0, 0, 0); \
      acc[0][3] = __builtin_amdgcn_mfma_f32_16x16x32_bf16(af0, bf3, acc[0][3], 0, 0, 0); \
      acc[1][0] = __builtin_amdgcn_mfma_f32_16x16x32_bf16(af1, bf0, acc[1][0], 0, 0, 0); \
      acc[1][1] = __builtin_amdgcn_mfma_f32_16x16x32_bf16(af1, bf1, acc[1][1], 0, 0, 0); \
      acc[1][2] = __builtin_amdgcn_mfma_f32_16x16x32_bf16(af1, bf2, acc[1][2], 0, 0, 0); \
      acc[1][3] = __builtin_amdgcn_mfma_f32_16x16x32_bf16(af1, bf3, acc[1][3], 0, 0, 0); \
    }                                                                          \
  }

  const int NT = KCAT / 64;  // 48
  STAGE3(0, 0);
  STAGE3(1, 1);
  int cur = 0;
  for (int it = 0; it < NT - 1; ++it) {
    // own stage-it landed when <=4 outstanding (only stage it+1 in flight)
    asm volatile("s_waitcnt vmcnt(4)" ::: "memory");
    __builtin_amdgcn_s_barrier();
    __builtin_amdgcn_sched_barrier(0);
    COMPUTE(cur);
    if (it < NT - 2) {
      int bs = cur + 2;
      if (bs >= 3) bs -= 3;
      STAGE3(bs, it + 2);  // issued after barrier: WAR-safe
    }
    cur = (cur == 2) ? 0 : cur + 1;
  }
  asm volatile("s_waitcnt vmcnt(0)" ::: "memory");
  __builtin_amdgcn_s_barrier();
  __builtin_amdgcn_sched_barrier(0);
  COMPUTE(cur);

  // C/D: col = lane&15, row = (lane>>4)*4 + reg
#pragma unroll
  for (int mi = 0; mi < 2; ++mi)
#pragma unroll
    for (int nj = 0; nj < 4; ++nj) {
      int rb = m0 + wr * 32 + mi * 16 + h * 4;
      int col = n0 + wc * 64 + nj * 16 + c16;
      out[(size_t)(rb + 0) * N_DIM + col] = acc[mi][nj][0];
      out[(size_t)(rb + 1) * N_DIM + col] = acc[mi][nj][1];
      out[(size_t)(rb + 2) * N_DIM + col] = acc[mi][nj][2];
      out[(size_t)(rb + 3) * N_DIM + col] = acc[mi][nj][3];
    }
#undef COMPUTE
#undef STAGE3
#undef AOFF
#undef BOFF
}

// ---------------------------------------------------------------------------
// Launch: 4 kernels.
// ---------------------------------------------------------------------------
extern "C" void kernel_launch(void* const* d_in, const int* in_sizes, int n_in,
                              void* d_out, int out_size, void* d_ws,
                              size_t ws_size, hipStream_t stream) {
  const float* x = (const float*)d_in[0];    // (C, N)
  const float* W = (const float*)d_in[1];    // (O, C)
  const float* eps = (const float*)d_in[2];  // (C, N)
  float* out = (float*)d_out;                // (O, N)
  char* ws = (char*)d_ws;

  double* s_d = (double*)(ws + 0);                          //   8 KB
  double* part = (double*)(ws + 8192);                      // 512 KB
  float* xT = (float*)(ws + 532480);                        //   4 MB
  float* gT = (float*)(ws + 4726784);                       //   4 MB
  float* partials = (float*)(ws + 8921088);                 //  16 MB (NZ=4)
  unsigned short* Acat = (unsigned short*)(ws + 42475520);  //  12 MB
  unsigned short* Bcat = (unsigned short*)(ws + 55058432);  //   6 MB

  prep_kernel<<<2304, 256, 0, stream>>>(x, eps, W, xT, gT, Acat, part);
  dist_kernel<<<1028, 256, 0, stream>>>(x, partials, part, s_d);
  topk_gather_kernel<<<1024, 128, 0, stream>>>(partials, s_d, xT, gT, Bcat);
  mfma_gemm<<<128, 512, 0, stream>>>(Acat, Bcat, out);
}

// Round 11
// 137.635 us; speedup vs baseline: 1.1134x; 1.1134x over previous
//
#include <hip/hip_runtime.h>

#define C_DIM 1024
#define N_DIM 1024
#define O_DIM 2048
#define K_NN  20
#define KCAT  3072  // 3 * 1024: [Whi,Whi,Wlo] x [hhi,hlo,hhi]
#define NZ    4     // dist GEMM split-K factor (round-2-validated partition)

typedef __attribute__((ext_vector_type(8))) short bf16x8;
typedef __attribute__((ext_vector_type(4))) float f32x4;

__device__ __forceinline__ unsigned short f2bf(float f) {
  unsigned u = __float_as_uint(f);
  unsigned r = (u + 0x7fffu + ((u >> 16) & 1u)) >> 16;  // RNE
  return (unsigned short)r;
}
__device__ __forceinline__ float bf2f(unsigned short h) {
  return __uint_as_float((unsigned)h << 16);
}

#define GLOAD16(gp, lp)                                                       \
  __builtin_amdgcn_global_load_lds(                                           \
      (const __attribute__((address_space(1))) unsigned int*)(uintptr_t)(gp), \
      (__attribute__((address_space(3))) unsigned int*)(uintptr_t)(lp), 16,   \
      0, 0)

// ---------------------------------------------------------------------------
// PREP+DIST (one launch, independent roles; dist tiles FIRST for dispatch
// priority on the critical path):
//   [0,544)      : fp32 sym split-K=4 dist GEMM (compact triangle, KZ=256)
//   [544,1568)   : transpose x/eps -> xT, gT=(1+eps)*x
//   [1568,2592)  : conv W -> Acat (split-bf16 hi,hi,lo; swizzled)
//   [2592,2608)  : column norms, fp64, self-contained (LDS reduce)
// 16KB shared LDS union across roles.
// ---------------------------------------------------------------------------
__global__ __launch_bounds__(256) void prep_dist_kernel(
    const float* __restrict__ x, const float* __restrict__ eps,
    const float* __restrict__ W, float* __restrict__ xT,
    float* __restrict__ gT, unsigned short* __restrict__ Acat,
    double* __restrict__ s_d, float* __restrict__ P) {
  __shared__ char smem[16384];
  int b = blockIdx.x;
  int t = threadIdx.x;
  if (b < 544) {
    // --- dist GEMM role: body identical to round-9 dist_kernel ---
    const int KZ = 256;
    int z = b / 136;
    int tid = b - z * 136;
    int by = 0, rem = tid;
    while (rem >= 16 - by) { rem -= 16 - by; ++by; }  // uniform, <=16 iters
    int bx = by + rem;  // by <= bx
    float(*Al)[64] = (float(*)[64])smem;            // [32][64]
    float(*Bl)[64] = (float(*)[64])(smem + 8192);   // [32][64]
    int tx = t & 15, ty = t >> 4;
    int m0 = by * 64, n0 = bx * 64;
    int kk = t >> 4, c4 = (t & 15) * 4;
    float acc[4][4] = {};
    int k0 = z * KZ;
    float4 a0 = *(const float4*)&x[(size_t)(k0 + kk) * N_DIM + m0 + c4];
    float4 a1 = *(const float4*)&x[(size_t)(k0 + kk + 16) * N_DIM + m0 + c4];
    float4 b0 = *(const float4*)&x[(size_t)(k0 + kk) * N_DIM + n0 + c4];
    float4 b1 = *(const float4*)&x[(size_t)(k0 + kk + 16) * N_DIM + n0 + c4];
    for (int kt = 0; kt < KZ / 32; ++kt) {
      __syncthreads();
      *(float4*)&Al[kk][c4] = a0;
      *(float4*)&Al[kk + 16][c4] = a1;
      *(float4*)&Bl[kk][c4] = b0;
      *(float4*)&Bl[kk + 16][c4] = b1;
      __syncthreads();
      if (kt + 1 < KZ / 32) {
        int kn = k0 + (kt + 1) * 32;
        a0 = *(const float4*)&x[(size_t)(kn + kk) * N_DIM + m0 + c4];
        a1 = *(const float4*)&x[(size_t)(kn + kk + 16) * N_DIM + m0 + c4];
        b0 = *(const float4*)&x[(size_t)(kn + kk) * N_DIM + n0 + c4];
        b1 = *(const float4*)&x[(size_t)(kn + kk + 16) * N_DIM + n0 + c4];
      }
#pragma unroll
      for (int q = 0; q < 32; ++q) {
        float4 a = *(const float4*)&Al[q][ty * 4];
        float4 bq = *(const float4*)&Bl[q][tx * 4];
        float am[4] = {a.x, a.y, a.z, a.w};
        float bn[4] = {bq.x, bq.y, bq.z, bq.w};
#pragma unroll
        for (int i = 0; i < 4; ++i)
#pragma unroll
          for (int j = 0; j < 4; ++j)
            acc[i][j] = fmaf(am[i], bn[j], acc[i][j]);
      }
    }
#pragma unroll
    for (int i = 0; i < 4; ++i) {
      float4 v = make_float4(acc[i][0], acc[i][1], acc[i][2], acc[i][3]);
      *(float4*)&P[((size_t)z * N_DIM + m0 + ty * 4 + i) * N_DIM + n0 + tx * 4] = v;
    }
    if (bx != by) {  // mirror (products commutative -> bitwise identical)
#pragma unroll
      for (int j = 0; j < 4; ++j) {
        float4 v = make_float4(acc[0][j], acc[1][j], acc[2][j], acc[3][j]);
        *(float4*)&P[((size_t)z * N_DIM + n0 + tx * 4 + j) * N_DIM + m0 + ty * 4] = v;
      }
    }
  } else if (b < 1568) {
    // --- transpose role ---
    int b2 = b - 544;
    float(*tx_)[33] = (float(*)[33])smem;            // [32][33]
    float(*tg_)[33] = (float(*)[33])(smem + 4224);   // [32][33]
    int bx = (b2 & 31) * 32, by = (b2 >> 5) * 32;
    int c = t & 31, r = t >> 5;
#pragma unroll
    for (int rr = 0; rr < 4; ++rr) {
      int row = by + r + 8 * rr;
      float xv = x[(size_t)row * N_DIM + bx + c];
      float ev = eps[(size_t)row * N_DIM + bx + c];
      tx_[r + 8 * rr][c] = xv;
      tg_[r + 8 * rr][c] = (1.f + ev) * xv;
    }
    __syncthreads();
#pragma unroll
    for (int rr = 0; rr < 4; ++rr) {
      xT[(size_t)(bx + r + 8 * rr) * C_DIM + by + c] = tx_[c][r + 8 * rr];
      gT[(size_t)(bx + r + 8 * rr) * C_DIM + by + c] = tg_[c][r + 8 * rr];
    }
  } else if (b < 2592) {
    // --- conv_w role ---
    int id = (b - 1568) * 256 + t;
    int m = id >> 7;
    int gh = id & 127;
    int g = gh >> 2, h = gh & 3;
    int c1 = g * 32 + h * 4;
    const float* wp = &W[(size_t)m * C_DIM];
    float4 v1 = *(const float4*)&wp[c1];
    float4 v2 = *(const float4*)&wp[c1 + 16];
    float vv[8] = {v1.x, v1.y, v1.z, v1.w, v2.x, v2.y, v2.z, v2.w};
    unsigned hi[8], lo[8];
#pragma unroll
    for (int i = 0; i < 8; ++i) {
      unsigned short hb = f2bf(vv[i]);
      hi[i] = hb;
      lo[i] = f2bf(vv[i] - bf2f(hb));
    }
    uint4 ph, pl;
    ph.x = hi[0] | (hi[1] << 16); ph.y = hi[2] | (hi[3] << 16);
    ph.z = hi[4] | (hi[5] << 16); ph.w = hi[6] | (hi[7] << 16);
    pl.x = lo[0] | (lo[1] << 16); pl.y = lo[2] | (lo[3] << 16);
    pl.z = lo[4] | (lo[5] << 16); pl.w = lo[6] | (lo[7] << 16);
    int s = g >> 1;
    int pc = ((g & 1) * 4 + h) ^ (m & 7);
    unsigned short* row = Acat + (size_t)m * KCAT;
    *(uint4*)(row + s * 64 + pc * 8) = ph;
    *(uint4*)(row + 1024 + s * 64 + pc * 8) = ph;
    *(uint4*)(row + 2048 + s * 64 + pc * 8) = pl;
  } else {
    // --- norms role: 16 blocks, fp64, LDS-reduced in-block ---
    double(*red)[64] = (double(*)[64])smem;  // [4][64]
    int nb = b - 2592;
    int j0 = nb * 64;
    int jj = t & 63, grp = t >> 6;
    double acc = 0.0;
    int c0 = grp * 256;
#pragma unroll 8
    for (int c = c0; c < c0 + 256; ++c) {
      float v = x[(size_t)c * N_DIM + j0 + jj];
      acc = fma((double)v, (double)v, acc);
    }
    red[grp][jj] = acc;
    __syncthreads();
    if (t < 64) {
      double s = ((red[0][t] + red[1][t]) + red[2][t]) + red[3][t];
      s_d[j0 + t] = s;
    }
  }
}

// ---------------------------------------------------------------------------
// TOPK + GATHER fused (unchanged from round 9).
// ---------------------------------------------------------------------------
__global__ __launch_bounds__(128) void topk_gather_kernel(
    const float* __restrict__ P, const double* __restrict__ s_d,
    const float* __restrict__ xT, const float* __restrict__ gT,
    unsigned short* __restrict__ Bcat) {
  __shared__ int sidx[K_NN];
  int i = blockIdx.x;
  int t = threadIdx.x;
  if (t < 64) {
    int l = t;
    double d[16];
#pragma unroll
    for (int q = 0; q < 16; ++q) {
      int j = q * 64 + l;
      double s = 0.0;
#pragma unroll
      for (int z = 0; z < NZ; ++z)
        s += (double)P[((size_t)z * N_DIM + i) * N_DIM + j];
      d[q] = 2.0 * s - s_d[j];
    }
    for (int r = 0; r < K_NN; ++r) {
      double bv = -1e300;
      int bj = N_DIM;
#pragma unroll
      for (int q = 0; q < 16; ++q) {
        int j = q * 64 + l;
        if (d[q] > bv) { bv = d[q]; bj = j; }
      }
#pragma unroll
      for (int off = 32; off; off >>= 1) {
        double ov = __shfl_xor(bv, off);
        int oj = __shfl_xor(bj, off);
        if (ov > bv || (ov == bv && oj < bj)) { bv = ov; bj = oj; }
      }
      if (l == 0) sidx[r] = bj;
      int kq = bj >> 6, kl = bj & 63;
      if (l == kl) {
#pragma unroll
        for (int q = 0; q < 16; ++q)
          if (q == kq) d[q] = -1e300;
      }
    }
  }
  __syncthreads();
  int n = i;
  int g = t >> 2, h = t & 3;
  int c1 = g * 32 + h * 4;
  int nb[K_NN];
#pragma unroll
  for (int k = 0; k < K_NN; ++k) nb[k] = sidx[k];
  float4 s1 = *(const float4*)&gT[(size_t)n * C_DIM + c1];
  float4 s2 = *(const float4*)&gT[(size_t)n * C_DIM + c1 + 16];
#pragma unroll
  for (int k = 0; k < K_NN; ++k) {
    const float* rp = &xT[(size_t)nb[k] * C_DIM];
    float4 v1 = *(const float4*)&rp[c1];
    float4 v2 = *(const float4*)&rp[c1 + 16];
    s1.x += v1.x; s1.y += v1.y; s1.z += v1.z; s1.w += v1.w;
    s2.x += v2.x; s2.y += v2.y; s2.z += v2.z; s2.w += v2.w;
  }
  float vv[8] = {s1.x, s1.y, s1.z, s1.w, s2.x, s2.y, s2.z, s2.w};
  unsigned hi[8], lo[8];
#pragma unroll
  for (int i2 = 0; i2 < 8; ++i2) {
    unsigned short hb = f2bf(vv[i2]);
    hi[i2] = hb;
    lo[i2] = f2bf(vv[i2] - bf2f(hb));
  }
  uint4 ph, pl;
  ph.x = hi[0] | (hi[1] << 16); ph.y = hi[2] | (hi[3] << 16);
  ph.z = hi[4] | (hi[5] << 16); ph.w = hi[6] | (hi[7] << 16);
  pl.x = lo[0] | (lo[1] << 16); pl.y = lo[2] | (lo[3] << 16);
  pl.z = lo[4] | (lo[5] << 16); pl.w = lo[6] | (lo[7] << 16);
  int s = g >> 1;
  int pc = ((g & 1) * 4 + h) ^ (n & 7);
  unsigned short* row = Bcat + (size_t)n * KCAT;
  *(uint4*)(row + s * 64 + pc * 8) = ph;
  *(uint4*)(row + 1024 + s * 64 + pc * 8) = pl;
  *(uint4*)(row + 2048 + s * 64 + pc * 8) = ph;
}

// ---------------------------------------------------------------------------
// bf16 MFMA GEMM: out (2048x1024) = Acat x Bcat^T. BM=64, BN=128, grid 256
// (FULL CU coverage, round-9's 128-grid left half the GPU idle). n-panel per
// XCD (bx=b&7): B 768KB L2-resident; A read once per XCD (L3 ~102MB). LDS
// 3buf x 24KB = 72KB -> 2 blocks/CU. 2-ahead prefetch, counted vmcnt(3).
// 8 waves = 2m x 4n, wave tile 32x32 (2x2 frags). k-ascending acc chains ->
// bitwise-identical output.
// ---------------------------------------------------------------------------
__global__ __launch_bounds__(512) void mfma_gemm(
    const unsigned short* __restrict__ Acat,
    const unsigned short* __restrict__ Bcat, float* __restrict__ out) {
  __shared__ unsigned short Alds[3][4096];  // 3 x 8KB  (64 rows x 64 k)
  __shared__ unsigned short Blds[3][8192];  // 3 x 16KB (128 rows x 64 k)
  int t = threadIdx.x;
  int w = t >> 6, l = t & 63;
  int b = blockIdx.x;
  int bx = b & 7;   // n-tile == XCD (8 tiles of 128)
  int by = b >> 3;  // m-tile (32 tiles of 64)
  int m0 = by * 64, n0 = bx * 128;
  int wr = w >> 2, wc = w & 3;  // 2m x 4n waves, wave tile 32x32
  int h = l >> 4, c16 = l & 15;
  int s8 = c16 & 7;

  // staging: A 64 rows x 8 chunks = 512 (thread t: 1), B 128 rows = 1024
  // chunks (thread t: rows t>>3 and 64+(t>>3)).
  const char* gA = (const char*)Acat + (size_t)(m0 + (t >> 3)) * (KCAT * 2) +
                   (t & 7) * 16;
  const char* gB = (const char*)Bcat + (size_t)(n0 + (t >> 3)) * (KCAT * 2) +
                   (t & 7) * 16;

#define AOFF(mi, wk) \
  ((wr * 32 + (mi)*16 + c16) * 64 + ((((wk)*4 + h) ^ s8) * 8))
#define BOFF(nj, wk) \
  ((wc * 32 + (nj)*16 + c16) * 64 + ((((wk)*4 + h) ^ s8) * 8))

  f32x4 acc[2][2] = {};

#define STAGE3(bufi, itv)                                                 \
  {                                                                       \
    const char* ga = gA + (size_t)(itv) * 128;                            \
    const char* gb = gB + (size_t)(itv) * 128;                            \
    GLOAD16(ga, (char*)&Alds[bufi][0] + t * 16);                          \
    GLOAD16(gb, (char*)&Blds[bufi][0] + t * 16);                          \
    GLOAD16(gb + (size_t)64 * (KCAT * 2),                                 \
            (char*)&Blds[bufi][0] + 8192 + t * 16);                       \
  }

#define COMPUTE(bufi)                                                          \
  {                                                                            \
    const unsigned short* Ab = &Alds[bufi][0];                                 \
    const unsigned short* Bb = &Blds[bufi][0];                                 \
    _Pragma("unroll") for (int wk = 0; wk < 2; ++wk) {                         \
      bf16x8 af0 = *(const bf16x8*)(Ab + AOFF(0, wk));                         \
      bf16x8 af1 = *(const bf16x8*)(Ab + AOFF(1, wk));                         \
      bf16x8 bf0 = *(const bf16x8*)(Bb + BOFF(0, wk));                         \
      bf16x8 bf1 = *(const bf16x8*)(Bb + BOFF(1, wk));                         \
      acc[0][0] = __builtin_amdgcn_mfma_f32_16x16x32_bf16(af0, bf0, acc[0][0], 0, 0, 0); \
      acc[0][1] = __builtin_amdgcn_mfma_f32_16x16x32_bf16(af0, bf1, acc[0][1], 0, 0, 0); \
      acc[1][0] = __builtin_amdgcn_mfma_f32_16x16x32_bf16(af1, bf0, acc[1][0], 0, 0, 0); \
      acc[1][1] = __builtin_amdgcn_mfma_f32_16x16x32_bf16(af1, bf1, acc[1][1], 0, 0, 0); \
    }                                                                          \
  }

  const int NT = KCAT / 64;  // 48
  STAGE3(0, 0);
  STAGE3(1, 1);
  int cur = 0;
  for (int it = 0; it < NT - 1; ++it) {
    // own stage-it (3 loads) landed when <=3 outstanding (stage it+1 only)
    asm volatile("s_waitcnt vmcnt(3)" ::: "memory");
    __builtin_amdgcn_s_barrier();
    __builtin_amdgcn_sched_barrier(0);
    COMPUTE(cur);
    if (it < NT - 2) {
      int bs = cur + 2;
      if (bs >= 3) bs -= 3;
      STAGE3(bs, it + 2);  // issued after barrier: WAR-safe
    }
    cur = (cur == 2) ? 0 : cur + 1;
  }
  asm volatile("s_waitcnt vmcnt(0)" ::: "memory");
  __builtin_amdgcn_s_barrier();
  __builtin_amdgcn_sched_barrier(0);
  COMPUTE(cur);

  // C/D: col = lane&15, row = (lane>>4)*4 + reg
#pragma unroll
  for (int mi = 0; mi < 2; ++mi)
#pragma unroll
    for (int nj = 0; nj < 2; ++nj) {
      int rb = m0 + wr * 32 + mi * 16 + h * 4;
      int col = n0 + wc * 32 + nj * 16 + c16;
      out[(size_t)(rb + 0) * N_DIM + col] = acc[mi][nj][0];
      out[(size_t)(rb + 1) * N_DIM + col] = acc[mi][nj][1];
      out[(size_t)(rb + 2) * N_DIM + col] = acc[mi][nj][2];
      out[(size_t)(rb + 3) * N_DIM + col] = acc[mi][nj][3];
    }
#undef COMPUTE
#undef STAGE3
#undef AOFF
#undef BOFF
}

// ---------------------------------------------------------------------------
// Launch: 3 kernels.
// ---------------------------------------------------------------------------
extern "C" void kernel_launch(void* const* d_in, const int* in_sizes, int n_in,
                              void* d_out, int out_size, void* d_ws,
                              size_t ws_size, hipStream_t stream) {
  const float* x = (const float*)d_in[0];    // (C, N)
  const float* W = (const float*)d_in[1];    // (O, C)
  const float* eps = (const float*)d_in[2];  // (C, N)
  float* out = (float*)d_out;                // (O, N)
  char* ws = (char*)d_ws;

  double* s_d = (double*)(ws + 0);                          //   8 KB
  float* xT = (float*)(ws + 532480);                        //   4 MB
  float* gT = (float*)(ws + 4726784);                       //   4 MB
  float* partials = (float*)(ws + 8921088);                 //  16 MB (NZ=4)
  unsigned short* Acat = (unsigned short*)(ws + 42475520);  //  12 MB
  unsigned short* Bcat = (unsigned short*)(ws + 55058432);  //   6 MB

  // 1: dist GEMM (first in grid) + transpose + conv_w + norms
  prep_dist_kernel<<<2608, 256, 0, stream>>>(x, eps, W, xT, gT, Acat, s_d,
                                             partials);
  // 2: top-20 + gather + Bcat build
  topk_gather_kernel<<<1024, 128, 0, stream>>>(partials, s_d, xT, gT, Bcat);
  // 3: out = W @ h via bf16 MFMA
  mfma_gemm<<<256, 512, 0, stream>>>(Acat, Bcat, out);
}

// Round 12
// 133.132 us; speedup vs baseline: 1.1510x; 1.0338x over previous
//
#include <hip/hip_runtime.h>

#define C_DIM 1024
#define N_DIM 1024
#define O_DIM 2048
#define K_NN  20
#define NZ    4     // dist GEMM split-K factor (round-2-validated partition)
// split-bf16 GEMM: 3 products (Whi*hhi, Whi*hlo, Wlo*hhi) over dedup'd
// operands Acat = [Whi,Wlo] (K'=2048), Bcat = [hhi,hlo] (K'=2048).
#define KA    2048  // Acat row length (ushorts)
#define KB    2048  // Bcat row length (ushorts)

typedef __attribute__((ext_vector_type(8))) short bf16x8;
typedef __attribute__((ext_vector_type(4))) float f32x4;

__device__ __forceinline__ unsigned short f2bf(float f) {
  unsigned u = __float_as_uint(f);
  unsigned r = (u + 0x7fffu + ((u >> 16) & 1u)) >> 16;  // RNE
  return (unsigned short)r;
}
__device__ __forceinline__ float bf2f(unsigned short h) {
  return __uint_as_float((unsigned)h << 16);
}

#define GLOAD16(gp, lp)                                                       \
  __builtin_amdgcn_global_load_lds(                                           \
      (const __attribute__((address_space(1))) unsigned int*)(uintptr_t)(gp), \
      (__attribute__((address_space(3))) unsigned int*)(uintptr_t)(lp), 16,   \
      0, 0)

// ---------------------------------------------------------------------------
// PREP+DIST (one launch, independent roles; dist tiles FIRST):
//   [0,544)      : fp32 sym split-K=4 dist GEMM (compact triangle, KZ=256)
//   [544,1568)   : transpose x/eps -> xT, gT=(1+eps)*x
//   [1568,2592)  : conv W -> Acat segs [hi, lo] (dedup'd; swizzled)
//   [2592,2608)  : column norms, fp64, self-contained (LDS reduce)
// ---------------------------------------------------------------------------
__global__ __launch_bounds__(256) void prep_dist_kernel(
    const float* __restrict__ x, const float* __restrict__ eps,
    const float* __restrict__ W, float* __restrict__ xT,
    float* __restrict__ gT, unsigned short* __restrict__ Acat,
    double* __restrict__ s_d, float* __restrict__ P) {
  __shared__ char smem[16384];
  int b = blockIdx.x;
  int t = threadIdx.x;
  if (b < 544) {
    // --- dist GEMM role (identical numerics to round 11) ---
    const int KZ = 256;
    int z = b / 136;
    int tid = b - z * 136;
    int by = 0, rem = tid;
    while (rem >= 16 - by) { rem -= 16 - by; ++by; }  // uniform, <=16 iters
    int bx = by + rem;  // by <= bx
    float(*Al)[64] = (float(*)[64])smem;            // [32][64]
    float(*Bl)[64] = (float(*)[64])(smem + 8192);   // [32][64]
    int tx = t & 15, ty = t >> 4;
    int m0 = by * 64, n0 = bx * 64;
    int kk = t >> 4, c4 = (t & 15) * 4;
    float acc[4][4] = {};
    int k0 = z * KZ;
    float4 a0 = *(const float4*)&x[(size_t)(k0 + kk) * N_DIM + m0 + c4];
    float4 a1 = *(const float4*)&x[(size_t)(k0 + kk + 16) * N_DIM + m0 + c4];
    float4 b0 = *(const float4*)&x[(size_t)(k0 + kk) * N_DIM + n0 + c4];
    float4 b1 = *(const float4*)&x[(size_t)(k0 + kk + 16) * N_DIM + n0 + c4];
    for (int kt = 0; kt < KZ / 32; ++kt) {
      __syncthreads();
      *(float4*)&Al[kk][c4] = a0;
      *(float4*)&Al[kk + 16][c4] = a1;
      *(float4*)&Bl[kk][c4] = b0;
      *(float4*)&Bl[kk + 16][c4] = b1;
      __syncthreads();
      if (kt + 1 < KZ / 32) {
        int kn = k0 + (kt + 1) * 32;
        a0 = *(const float4*)&x[(size_t)(kn + kk) * N_DIM + m0 + c4];
        a1 = *(const float4*)&x[(size_t)(kn + kk + 16) * N_DIM + m0 + c4];
        b0 = *(const float4*)&x[(size_t)(kn + kk) * N_DIM + n0 + c4];
        b1 = *(const float4*)&x[(size_t)(kn + kk + 16) * N_DIM + n0 + c4];
      }
#pragma unroll
      for (int q = 0; q < 32; ++q) {
        float4 a = *(const float4*)&Al[q][ty * 4];
        float4 bq = *(const float4*)&Bl[q][tx * 4];
        float am[4] = {a.x, a.y, a.z, a.w};
        float bn[4] = {bq.x, bq.y, bq.z, bq.w};
#pragma unroll
        for (int i = 0; i < 4; ++i)
#pragma unroll
          for (int j = 0; j < 4; ++j)
            acc[i][j] = fmaf(am[i], bn[j], acc[i][j]);
      }
    }
#pragma unroll
    for (int i = 0; i < 4; ++i) {
      float4 v = make_float4(acc[i][0], acc[i][1], acc[i][2], acc[i][3]);
      *(float4*)&P[((size_t)z * N_DIM + m0 + ty * 4 + i) * N_DIM + n0 + tx * 4] = v;
    }
    if (bx != by) {  // mirror (products commutative -> bitwise identical)
#pragma unroll
      for (int j = 0; j < 4; ++j) {
        float4 v = make_float4(acc[0][j], acc[1][j], acc[2][j], acc[3][j]);
        *(float4*)&P[((size_t)z * N_DIM + n0 + tx * 4 + j) * N_DIM + m0 + ty * 4] = v;
      }
    }
  } else if (b < 1568) {
    // --- transpose role ---
    int b2 = b - 544;
    float(*tx_)[33] = (float(*)[33])smem;            // [32][33]
    float(*tg_)[33] = (float(*)[33])(smem + 4224);   // [32][33]
    int bx = (b2 & 31) * 32, by = (b2 >> 5) * 32;
    int c = t & 31, r = t >> 5;
#pragma unroll
    for (int rr = 0; rr < 4; ++rr) {
      int row = by + r + 8 * rr;
      float xv = x[(size_t)row * N_DIM + bx + c];
      float ev = eps[(size_t)row * N_DIM + bx + c];
      tx_[r + 8 * rr][c] = xv;
      tg_[r + 8 * rr][c] = (1.f + ev) * xv;
    }
    __syncthreads();
#pragma unroll
    for (int rr = 0; rr < 4; ++rr) {
      xT[(size_t)(bx + r + 8 * rr) * C_DIM + by + c] = tx_[c][r + 8 * rr];
      gT[(size_t)(bx + r + 8 * rr) * C_DIM + by + c] = tg_[c][r + 8 * rr];
    }
  } else if (b < 2592) {
    // --- conv_w role: W -> Acat segs [hi, lo], swizzled, row = KA ushorts ---
    int id = (b - 1568) * 256 + t;
    int m = id >> 7;
    int gh = id & 127;
    int g = gh >> 2, h = gh & 3;
    int c1 = g * 32 + h * 4;
    const float* wp = &W[(size_t)m * C_DIM];
    float4 v1 = *(const float4*)&wp[c1];
    float4 v2 = *(const float4*)&wp[c1 + 16];
    float vv[8] = {v1.x, v1.y, v1.z, v1.w, v2.x, v2.y, v2.z, v2.w};
    unsigned hi[8], lo[8];
#pragma unroll
    for (int i = 0; i < 8; ++i) {
      unsigned short hb = f2bf(vv[i]);
      hi[i] = hb;
      lo[i] = f2bf(vv[i] - bf2f(hb));
    }
    uint4 ph, pl;
    ph.x = hi[0] | (hi[1] << 16); ph.y = hi[2] | (hi[3] << 16);
    ph.z = hi[4] | (hi[5] << 16); ph.w = hi[6] | (hi[7] << 16);
    pl.x = lo[0] | (lo[1] << 16); pl.y = lo[2] | (lo[3] << 16);
    pl.z = lo[4] | (lo[5] << 16); pl.w = lo[6] | (lo[7] << 16);
    int s = g >> 1;
    int pc = ((g & 1) * 4 + h) ^ (m & 7);
    unsigned short* row = Acat + (size_t)m * KA;
    *(uint4*)(row + s * 64 + pc * 8) = ph;
    *(uint4*)(row + 1024 + s * 64 + pc * 8) = pl;
  } else {
    // --- norms role: 16 blocks, fp64, LDS-reduced in-block ---
    double(*red)[64] = (double(*)[64])smem;  // [4][64]
    int nb = b - 2592;
    int j0 = nb * 64;
    int jj = t & 63, grp = t >> 6;
    double acc = 0.0;
    int c0 = grp * 256;
#pragma unroll 8
    for (int c = c0; c < c0 + 256; ++c) {
      float v = x[(size_t)c * N_DIM + j0 + jj];
      acc = fma((double)v, (double)v, acc);
    }
    red[grp][jj] = acc;
    __syncthreads();
    if (t < 64) {
      double s = ((red[0][t] + red[1][t]) + red[2][t]) + red[3][t];
      s_d[j0 + t] = s;
    }
  }
}

// ---------------------------------------------------------------------------
// TOPK + GATHER fused. Topk uses packed fp64 keys: m = s_d - 2*dot (>0),
// low 10 mantissa bits replaced by j -> argmax+tie->lowest-index becomes a
// pure fmin reduce (mask blur <= 2^-32, 3 orders below fp32-level gaps).
// ---------------------------------------------------------------------------
__global__ __launch_bounds__(128) void topk_gather_kernel(
    const float* __restrict__ P, const double* __restrict__ s_d,
    const float* __restrict__ xT, const float* __restrict__ gT,
    unsigned short* __restrict__ Bcat) {
  __shared__ int sidx[K_NN];
  int i = blockIdx.x;
  int t = threadIdx.x;
  if (t < 64) {
    int l = t;
    double d[16];
#pragma unroll
    for (int q = 0; q < 16; ++q) {
      int j = q * 64 + l;
      double s = 0.0;
#pragma unroll
      for (int z = 0; z < NZ; ++z)
        s += (double)P[((size_t)z * N_DIM + i) * N_DIM + j];
      double m = s_d[j] - 2.0 * s;  // = -dist, positive ~1100
      unsigned long long bits = __double_as_longlong(m);
      bits = (bits & ~0x3FFull) | (unsigned long long)j;
      d[q] = __longlong_as_double(bits);
    }
    for (int r = 0; r < K_NN; ++r) {
      // min-key = max dist, tie -> lowest j (packed in low bits)
      double m0a = fmin(d[0], d[1]),   m0b = fmin(d[2], d[3]);
      double m0c = fmin(d[4], d[5]),   m0d = fmin(d[6], d[7]);
      double m0e = fmin(d[8], d[9]),   m0f = fmin(d[10], d[11]);
      double m0g = fmin(d[12], d[13]), m0h = fmin(d[14], d[15]);
      double m1a = fmin(m0a, m0b), m1b = fmin(m0c, m0d);
      double m1c = fmin(m0e, m0f), m1d = fmin(m0g, m0h);
      double bv = fmin(fmin(m1a, m1b), fmin(m1c, m1d));
#pragma unroll
      for (int off = 32; off; off >>= 1)
        bv = fmin(bv, __shfl_xor(bv, off));
      int bj = (int)(__double_as_longlong(bv) & 0x3FFull);
      if (l == 0) sidx[r] = bj;
      int kq = bj >> 6, kl = bj & 63;
      if (l == kl) {
#pragma unroll
        for (int q = 0; q < 16; ++q)
          if (q == kq) d[q] = __longlong_as_double(0x7FF0000000000000ull);
      }
    }
  }
  __syncthreads();
  // --- gather role: Bcat segs [hi, lo], row = KB ushorts ---
  int n = i;
  int g = t >> 2, h = t & 3;
  int c1 = g * 32 + h * 4;
  int nb[K_NN];
#pragma unroll
  for (int k = 0; k < K_NN; ++k) nb[k] = sidx[k];
  float4 s1 = *(const float4*)&gT[(size_t)n * C_DIM + c1];
  float4 s2 = *(const float4*)&gT[(size_t)n * C_DIM + c1 + 16];
#pragma unroll
  for (int k = 0; k < K_NN; ++k) {
    const float* rp = &xT[(size_t)nb[k] * C_DIM];
    float4 v1 = *(const float4*)&rp[c1];
    float4 v2 = *(const float4*)&rp[c1 + 16];
    s1.x += v1.x; s1.y += v1.y; s1.z += v1.z; s1.w += v1.w;
    s2.x += v2.x; s2.y += v2.y; s2.z += v2.z; s2.w += v2.w;
  }
  float vv[8] = {s1.x, s1.y, s1.z, s1.w, s2.x, s2.y, s2.z, s2.w};
  unsigned hi[8], lo[8];
#pragma unroll
  for (int i2 = 0; i2 < 8; ++i2) {
    unsigned short hb = f2bf(vv[i2]);
    hi[i2] = hb;
    lo[i2] = f2bf(vv[i2] - bf2f(hb));
  }
  uint4 ph, pl;
  ph.x = hi[0] | (hi[1] << 16); ph.y = hi[2] | (hi[3] << 16);
  ph.z = hi[4] | (hi[5] << 16); ph.w = hi[6] | (hi[7] << 16);
  pl.x = lo[0] | (lo[1] << 16); pl.y = lo[2] | (lo[3] << 16);
  pl.z = lo[4] | (lo[5] << 16); pl.w = lo[6] | (lo[7] << 16);
  int s = g >> 1;
  int pc = ((g & 1) * 4 + h) ^ (n & 7);
  unsigned short* row = Bcat + (size_t)n * KB;
  *(uint4*)(row + s * 64 + pc * 8) = ph;
  *(uint4*)(row + 1024 + s * 64 + pc * 8) = pl;
}

// ---------------------------------------------------------------------------
// bf16 MFMA GEMM over dedup'd operands: 48 K-steps select per-step segment
// offsets: it[0,16)=Whi*hhi, [16,32)=Whi*hlo, [32,48)=Wlo*hhi — same products
// in the same order as the 3-seg layout -> bitwise-identical output. BM=64,
// BN=128, grid 256 full-CU, n-panel per XCD, 3 LDS bufs, 2-ahead prefetch,
// counted vmcnt(3). A L3 traffic 8MB x 8 XCDs = 64MB (was 96).
// ---------------------------------------------------------------------------
__global__ __launch_bounds__(512) void mfma_gemm(
    const unsigned short* __restrict__ Acat,
    const unsigned short* __restrict__ Bcat, float* __restrict__ out) {
  __shared__ unsigned short Alds[3][4096];  // 3 x 8KB  (64 rows x 64 k)
  __shared__ unsigned short Blds[3][8192];  // 3 x 16KB (128 rows x 64 k)
  int t = threadIdx.x;
  int w = t >> 6, l = t & 63;
  int b = blockIdx.x;
  int bx = b & 7;   // n-tile == XCD (8 tiles of 128)
  int by = b >> 3;  // m-tile (32 tiles of 64)
  int m0 = by * 64, n0 = bx * 128;
  int wr = w >> 2, wc = w & 3;  // 2m x 4n waves, wave tile 32x32
  int h = l >> 4, c16 = l & 15;
  int s8 = c16 & 7;

  const char* gA = (const char*)Acat + (size_t)(m0 + (t >> 3)) * (KA * 2) +
                   (t & 7) * 16;
  const char* gB = (const char*)Bcat + (size_t)(n0 + (t >> 3)) * (KB * 2) +
                   (t & 7) * 16;

#define AOFF(mi, wk) \
  ((wr * 32 + (mi)*16 + c16) * 64 + ((((wk)*4 + h) ^ s8) * 8))
#define BOFF(nj, wk) \
  ((wc * 32 + (nj)*16 + c16) * 64 + ((((wk)*4 + h) ^ s8) * 8))

  f32x4 acc[2][2] = {};

  // per-step operand segment offsets (bytes): seg = 1024 ushorts = 2048 B
#define STAGE3(bufi, itv)                                                 \
  {                                                                       \
    size_t aoff = (size_t)(((itv)&15) * 128) + (((itv) >= 32) ? 2048 : 0);\
    size_t boff = (size_t)(((itv)&15) * 128) +                            \
                  (((((itv) >> 4) == 1)) ? 2048 : 0);                     \
    GLOAD16(gA + aoff, (char*)&Alds[bufi][0] + t * 16);                   \
    GLOAD16(gB + boff, (char*)&Blds[bufi][0] + t * 16);                   \
    GLOAD16(gB + (size_t)64 * (KB * 2) + boff,                            \
            (char*)&Blds[bufi][0] + 8192 + t * 16);                       \
  }

#define COMPUTE(bufi)                                                          \
  {                                                                            \
    const unsigned short* Ab = &Alds[bufi][0];                                 \
    const unsigned short* Bb = &Blds[bufi][0];                                 \
    _Pragma("unroll") for (int wk = 0; wk < 2; ++wk) {                         \
      bf16x8 af0 = *(const bf16x8*)(Ab + AOFF(0, wk));                         \
      bf16x8 af1 = *(const bf16x8*)(Ab + AOFF(1, wk));                         \
      bf16x8 bf0 = *(const bf16x8*)(Bb + BOFF(0, wk));                         \
      bf16x8 bf1 = *(const bf16x8*)(Bb + BOFF(1, wk));                         \
      acc[0][0] = __builtin_amdgcn_mfma_f32_16x16x32_bf16(af0, bf0, acc[0][0], 0, 0, 0); \
      acc[0][1] = __builtin_amdgcn_mfma_f32_16x16x32_bf16(af0, bf1, acc[0][1], 0, 0, 0); \
      acc[1][0] = __builtin_amdgcn_mfma_f32_16x16x32_bf16(af1, bf0, acc[1][0], 0, 0, 0); \
      acc[1][1] = __builtin_amdgcn_mfma_f32_16x16x32_bf16(af1, bf1, acc[1][1], 0, 0, 0); \
    }                                                                          \
  }

  const int NT = 48;  // 3 products x 16 K-steps
  STAGE3(0, 0);
  STAGE3(1, 1);
  int cur = 0;
  for (int it = 0; it < NT - 1; ++it) {
    // own stage-it (3 loads) landed when <=3 outstanding (stage it+1 only)
    asm volatile("s_waitcnt vmcnt(3)" ::: "memory");
    __builtin_amdgcn_s_barrier();
    __builtin_amdgcn_sched_barrier(0);
    COMPUTE(cur);
    if (it < NT - 2) {
      int bs = cur + 2;
      if (bs >= 3) bs -= 3;
      STAGE3(bs, it + 2);  // issued after barrier: WAR-safe
    }
    cur = (cur == 2) ? 0 : cur + 1;
  }
  asm volatile("s_waitcnt vmcnt(0)" ::: "memory");
  __builtin_amdgcn_s_barrier();
  __builtin_amdgcn_sched_barrier(0);
  COMPUTE(cur);

  // C/D: col = lane&15, row = (lane>>4)*4 + reg
#pragma unroll
  for (int mi = 0; mi < 2; ++mi)
#pragma unroll
    for (int nj = 0; nj < 2; ++nj) {
      int rb = m0 + wr * 32 + mi * 16 + h * 4;
      int col = n0 + wc * 32 + nj * 16 + c16;
      out[(size_t)(rb + 0) * N_DIM + col] = acc[mi][nj][0];
      out[(size_t)(rb + 1) * N_DIM + col] = acc[mi][nj][1];
      out[(size_t)(rb + 2) * N_DIM + col] = acc[mi][nj][2];
      out[(size_t)(rb + 3) * N_DIM + col] = acc[mi][nj][3];
    }
#undef COMPUTE
#undef STAGE3
#undef AOFF
#undef BOFF
}

// ---------------------------------------------------------------------------
// Launch: 3 kernels.
// ---------------------------------------------------------------------------
extern "C" void kernel_launch(void* const* d_in, const int* in_sizes, int n_in,
                              void* d_out, int out_size, void* d_ws,
                              size_t ws_size, hipStream_t stream) {
  const float* x = (const float*)d_in[0];    // (C, N)
  const float* W = (const float*)d_in[1];    // (O, C)
  const float* eps = (const float*)d_in[2];  // (C, N)
  float* out = (float*)d_out;                // (O, N)
  char* ws = (char*)d_ws;

  double* s_d = (double*)(ws + 0);                          //   8 KB
  float* xT = (float*)(ws + 532480);                        //   4 MB
  float* gT = (float*)(ws + 4726784);                       //   4 MB
  float* partials = (float*)(ws + 8921088);                 //  16 MB (NZ=4)
  unsigned short* Acat = (unsigned short*)(ws + 42475520);  //   8 MB
  unsigned short* Bcat = (unsigned short*)(ws + 55058432);  //   4 MB

  // 1: dist GEMM (first in grid) + transpose + conv_w + norms
  prep_dist_kernel<<<2608, 256, 0, stream>>>(x, eps, W, xT, gT, Acat, s_d,
                                             partials);
  // 2: top-20 + gather + Bcat build
  topk_gather_kernel<<<1024, 128, 0, stream>>>(partials, s_d, xT, gT, Bcat);
  // 3: out = W @ h via bf16 MFMA
  mfma_gemm<<<256, 512, 0, stream>>>(Acat, Bcat, out);
}

// Round 13
// 127.070 us; speedup vs baseline: 1.2060x; 1.0477x over previous
//
#include <hip/hip_runtime.h>

#define C_DIM 1024
#define N_DIM 1024
#define O_DIM 2048
#define K_NN  20
#define NZ    4     // dist GEMM split-K factor (round-2-validated partition)
// split-bf16 GEMM: 3 products (Whi*hhi, Whi*hlo, Wlo*hhi) over dedup'd
// operands Acat = [Whi,Wlo] (K'=2048), Bcat = [hhi,hlo] (K'=2048).
#define KA    2048  // Acat row length (ushorts)
#define KB    2048  // Bcat row length (ushorts)

typedef __attribute__((ext_vector_type(8))) short bf16x8;
typedef __attribute__((ext_vector_type(4))) float f32x4;

__device__ __forceinline__ unsigned short f2bf(float f) {
  unsigned u = __float_as_uint(f);
  unsigned r = (u + 0x7fffu + ((u >> 16) & 1u)) >> 16;  // RNE
  return (unsigned short)r;
}
__device__ __forceinline__ float bf2f(unsigned short h) {
  return __uint_as_float((unsigned)h << 16);
}

#define GLOAD16(gp, lp)                                                       \
  __builtin_amdgcn_global_load_lds(                                           \
      (const __attribute__((address_space(1))) unsigned int*)(uintptr_t)(gp), \
      (__attribute__((address_space(3))) unsigned int*)(uintptr_t)(lp), 16,   \
      0, 0)

// ---------------------------------------------------------------------------
// PREP+DIST (one launch, independent roles; dist tiles FIRST):
//   [0,544)      : fp32 sym split-K=4 dist GEMM (compact triangle, KZ=256)
//   [544,1568)   : transpose x/eps -> xT, gT=(1+eps)*x
//   [1568,2592)  : conv W -> Acat segs [hi, lo] (dedup'd; swizzled)
//   [2592,2608)  : column norms, fp64, self-contained (LDS reduce)
// ---------------------------------------------------------------------------
__global__ __launch_bounds__(256) void prep_dist_kernel(
    const float* __restrict__ x, const float* __restrict__ eps,
    const float* __restrict__ W, float* __restrict__ xT,
    float* __restrict__ gT, unsigned short* __restrict__ Acat,
    double* __restrict__ s_d, float* __restrict__ P) {
  __shared__ char smem[16384];
  int b = blockIdx.x;
  int t = threadIdx.x;
  if (b < 544) {
    // --- dist GEMM role (identical numerics to round 12) ---
    const int KZ = 256;
    int z = b / 136;
    int tid = b - z * 136;
    int by = 0, rem = tid;
    while (rem >= 16 - by) { rem -= 16 - by; ++by; }  // uniform, <=16 iters
    int bx = by + rem;  // by <= bx
    float(*Al)[64] = (float(*)[64])smem;            // [32][64]
    float(*Bl)[64] = (float(*)[64])(smem + 8192);   // [32][64]
    int tx = t & 15, ty = t >> 4;
    int m0 = by * 64, n0 = bx * 64;
    int kk = t >> 4, c4 = (t & 15) * 4;
    float acc[4][4] = {};
    int k0 = z * KZ;
    float4 a0 = *(const float4*)&x[(size_t)(k0 + kk) * N_DIM + m0 + c4];
    float4 a1 = *(const float4*)&x[(size_t)(k0 + kk + 16) * N_DIM + m0 + c4];
    float4 b0 = *(const float4*)&x[(size_t)(k0 + kk) * N_DIM + n0 + c4];
    float4 b1 = *(const float4*)&x[(size_t)(k0 + kk + 16) * N_DIM + n0 + c4];
    for (int kt = 0; kt < KZ / 32; ++kt) {
      __syncthreads();
      *(float4*)&Al[kk][c4] = a0;
      *(float4*)&Al[kk + 16][c4] = a1;
      *(float4*)&Bl[kk][c4] = b0;
      *(float4*)&Bl[kk + 16][c4] = b1;
      __syncthreads();
      if (kt + 1 < KZ / 32) {
        int kn = k0 + (kt + 1) * 32;
        a0 = *(const float4*)&x[(size_t)(kn + kk) * N_DIM + m0 + c4];
        a1 = *(const float4*)&x[(size_t)(kn + kk + 16) * N_DIM + m0 + c4];
        b0 = *(const float4*)&x[(size_t)(kn + kk) * N_DIM + n0 + c4];
        b1 = *(const float4*)&x[(size_t)(kn + kk + 16) * N_DIM + n0 + c4];
      }
#pragma unroll
      for (int q = 0; q < 32; ++q) {
        float4 a = *(const float4*)&Al[q][ty * 4];
        float4 bq = *(const float4*)&Bl[q][tx * 4];
        float am[4] = {a.x, a.y, a.z, a.w};
        float bn[4] = {bq.x, bq.y, bq.z, bq.w};
#pragma unroll
        for (int i = 0; i < 4; ++i)
#pragma unroll
          for (int j = 0; j < 4; ++j)
            acc[i][j] = fmaf(am[i], bn[j], acc[i][j]);
      }
    }
#pragma unroll
    for (int i = 0; i < 4; ++i) {
      float4 v = make_float4(acc[i][0], acc[i][1], acc[i][2], acc[i][3]);
      *(float4*)&P[((size_t)z * N_DIM + m0 + ty * 4 + i) * N_DIM + n0 + tx * 4] = v;
    }
    if (bx != by) {  // mirror (products commutative -> bitwise identical)
#pragma unroll
      for (int j = 0; j < 4; ++j) {
        float4 v = make_float4(acc[0][j], acc[1][j], acc[2][j], acc[3][j]);
        *(float4*)&P[((size_t)z * N_DIM + n0 + tx * 4 + j) * N_DIM + m0 + ty * 4] = v;
      }
    }
  } else if (b < 1568) {
    // --- transpose role ---
    int b2 = b - 544;
    float(*tx_)[33] = (float(*)[33])smem;            // [32][33]
    float(*tg_)[33] = (float(*)[33])(smem + 4224);   // [32][33]
    int bx = (b2 & 31) * 32, by = (b2 >> 5) * 32;
    int c = t & 31, r = t >> 5;
#pragma unroll
    for (int rr = 0; rr < 4; ++rr) {
      int row = by + r + 8 * rr;
      float xv = x[(size_t)row * N_DIM + bx + c];
      float ev = eps[(size_t)row * N_DIM + bx + c];
      tx_[r + 8 * rr][c] = xv;
      tg_[r + 8 * rr][c] = (1.f + ev) * xv;
    }
    __syncthreads();
#pragma unroll
    for (int rr = 0; rr < 4; ++rr) {
      xT[(size_t)(bx + r + 8 * rr) * C_DIM + by + c] = tx_[c][r + 8 * rr];
      gT[(size_t)(bx + r + 8 * rr) * C_DIM + by + c] = tg_[c][r + 8 * rr];
    }
  } else if (b < 2592) {
    // --- conv_w role: W -> Acat segs [hi, lo], swizzled, row = KA ushorts ---
    int id = (b - 1568) * 256 + t;
    int m = id >> 7;
    int gh = id & 127;
    int g = gh >> 2, h = gh & 3;
    int c1 = g * 32 + h * 4;
    const float* wp = &W[(size_t)m * C_DIM];
    float4 v1 = *(const float4*)&wp[c1];
    float4 v2 = *(const float4*)&wp[c1 + 16];
    float vv[8] = {v1.x, v1.y, v1.z, v1.w, v2.x, v2.y, v2.z, v2.w};
    unsigned hi[8], lo[8];
#pragma unroll
    for (int i = 0; i < 8; ++i) {
      unsigned short hb = f2bf(vv[i]);
      hi[i] = hb;
      lo[i] = f2bf(vv[i] - bf2f(hb));
    }
    uint4 ph, pl;
    ph.x = hi[0] | (hi[1] << 16); ph.y = hi[2] | (hi[3] << 16);
    ph.z = hi[4] | (hi[5] << 16); ph.w = hi[6] | (hi[7] << 16);
    pl.x = lo[0] | (lo[1] << 16); pl.y = lo[2] | (lo[3] << 16);
    pl.z = lo[4] | (lo[5] << 16); pl.w = lo[6] | (lo[7] << 16);
    int s = g >> 1;
    int pc = ((g & 1) * 4 + h) ^ (m & 7);
    unsigned short* row = Acat + (size_t)m * KA;
    *(uint4*)(row + s * 64 + pc * 8) = ph;
    *(uint4*)(row + 1024 + s * 64 + pc * 8) = pl;
  } else {
    // --- norms role: 16 blocks, fp64, LDS-reduced in-block ---
    double(*red)[64] = (double(*)[64])smem;  // [4][64]
    int nb = b - 2592;
    int j0 = nb * 64;
    int jj = t & 63, grp = t >> 6;
    double acc = 0.0;
    int c0 = grp * 256;
#pragma unroll 8
    for (int c = c0; c < c0 + 256; ++c) {
      float v = x[(size_t)c * N_DIM + j0 + jj];
      acc = fma((double)v, (double)v, acc);
    }
    red[grp][jj] = acc;
    __syncthreads();
    if (t < 64) {
      double s = ((red[0][t] + red[1][t]) + red[2][t]) + red[3][t];
      s_d[j0 + t] = s;
    }
  }
}

// ---------------------------------------------------------------------------
// TOPK + GATHER fused. Topk uses packed fp64 keys: m = s_d - 2*dot (>0),
// low 10 mantissa bits replaced by j -> argmax+tie->lowest-index becomes a
// pure fmin reduce (mask blur <= 2^-32, 3 orders below fp32-level gaps).
// ---------------------------------------------------------------------------
__global__ __launch_bounds__(128) void topk_gather_kernel(
    const float* __restrict__ P, const double* __restrict__ s_d,
    const float* __restrict__ xT, const float* __restrict__ gT,
    unsigned short* __restrict__ Bcat) {
  __shared__ int sidx[K_NN];
  int i = blockIdx.x;
  int t = threadIdx.x;
  if (t < 64) {
    int l = t;
    double d[16];
#pragma unroll
    for (int q = 0; q < 16; ++q) {
      int j = q * 64 + l;
      double s = 0.0;
#pragma unroll
      for (int z = 0; z < NZ; ++z)
        s += (double)P[((size_t)z * N_DIM + i) * N_DIM + j];
      double m = s_d[j] - 2.0 * s;  // = -dist, positive ~1100
      unsigned long long bits = __double_as_longlong(m);
      bits = (bits & ~0x3FFull) | (unsigned long long)j;
      d[q] = __longlong_as_double(bits);
    }
    for (int r = 0; r < K_NN; ++r) {
      // min-key = max dist, tie -> lowest j (packed in low bits)
      double m0a = fmin(d[0], d[1]),   m0b = fmin(d[2], d[3]);
      double m0c = fmin(d[4], d[5]),   m0d = fmin(d[6], d[7]);
      double m0e = fmin(d[8], d[9]),   m0f = fmin(d[10], d[11]);
      double m0g = fmin(d[12], d[13]), m0h = fmin(d[14], d[15]);
      double m1a = fmin(m0a, m0b), m1b = fmin(m0c, m0d);
      double m1c = fmin(m0e, m0f), m1d = fmin(m0g, m0h);
      double bv = fmin(fmin(m1a, m1b), fmin(m1c, m1d));
#pragma unroll
      for (int off = 32; off; off >>= 1)
        bv = fmin(bv, __shfl_xor(bv, off));
      int bj = (int)(__double_as_longlong(bv) & 0x3FFull);
      if (l == 0) sidx[r] = bj;
      int kq = bj >> 6, kl = bj & 63;
      if (l == kl) {
#pragma unroll
        for (int q = 0; q < 16; ++q)
          if (q == kq) d[q] = __longlong_as_double(0x7FF0000000000000ull);
      }
    }
  }
  __syncthreads();
  // --- gather role: Bcat segs [hi, lo], row = KB ushorts ---
  int n = i;
  int g = t >> 2, h = t & 3;
  int c1 = g * 32 + h * 4;
  int nb[K_NN];
#pragma unroll
  for (int k = 0; k < K_NN; ++k) nb[k] = sidx[k];
  float4 s1 = *(const float4*)&gT[(size_t)n * C_DIM + c1];
  float4 s2 = *(const float4*)&gT[(size_t)n * C_DIM + c1 + 16];
#pragma unroll
  for (int k = 0; k < K_NN; ++k) {
    const float* rp = &xT[(size_t)nb[k] * C_DIM];
    float4 v1 = *(const float4*)&rp[c1];
    float4 v2 = *(const float4*)&rp[c1 + 16];
    s1.x += v1.x; s1.y += v1.y; s1.z += v1.z; s1.w += v1.w;
    s2.x += v2.x; s2.y += v2.y; s2.z += v2.z; s2.w += v2.w;
  }
  float vv[8] = {s1.x, s1.y, s1.z, s1.w, s2.x, s2.y, s2.z, s2.w};
  unsigned hi[8], lo[8];
#pragma unroll
  for (int i2 = 0; i2 < 8; ++i2) {
    unsigned short hb = f2bf(vv[i2]);
    hi[i2] = hb;
    lo[i2] = f2bf(vv[i2] - bf2f(hb));
  }
  uint4 ph, pl;
  ph.x = hi[0] | (hi[1] << 16); ph.y = hi[2] | (hi[3] << 16);
  ph.z = hi[4] | (hi[5] << 16); ph.w = hi[6] | (hi[7] << 16);
  pl.x = lo[0] | (lo[1] << 16); pl.y = lo[2] | (lo[3] << 16);
  pl.z = lo[4] | (lo[5] << 16); pl.w = lo[6] | (lo[7] << 16);
  int s = g >> 1;
  int pc = ((g & 1) * 4 + h) ^ (n & 7);
  unsigned short* row = Bcat + (size_t)n * KB;
  *(uint4*)(row + s * 64 + pc * 8) = ph;
  *(uint4*)(row + 1024 + s * 64 + pc * 8) = pl;
}

// ---------------------------------------------------------------------------
// bf16 MFMA GEMM over dedup'd operands (48 steps: [0,16)=Whi*hhi,
// [16,32)=Whi*hlo, [32,48)=Wlo*hhi). ROUND-13 CHANGE: XCD owns an M-PANEL
// (not n-panel): xcd = b&7 -> W-rows [xcd*256, xcd*256+256) (Acat panel 1MB,
// L2-resident); n-tiles cycle in groups of 4 consecutive blocks (B-panel
// 512KB hot). L3 traffic: A 8MB (first touch) + B 4MB x 8 XCDs = 40MB
// (was 68MB with n-panel ownership). MFMA order unchanged -> bitwise
// identical. BM=64, BN=128, grid 256, 3 LDS bufs, 2-ahead, vmcnt(3).
// ---------------------------------------------------------------------------
__global__ __launch_bounds__(512) void mfma_gemm(
    const unsigned short* __restrict__ Acat,
    const unsigned short* __restrict__ Bcat, float* __restrict__ out) {
  __shared__ unsigned short Alds[3][4096];  // 3 x 8KB  (64 rows x 64 k)
  __shared__ unsigned short Blds[3][8192];  // 3 x 16KB (128 rows x 64 k)
  int t = threadIdx.x;
  int w = t >> 6, l = t & 63;
  int b = blockIdx.x;
  int xcd = b & 7;  // XCD owns m-panel [xcd*256, xcd*256+256)
  int j = b >> 3;   // 0..31 within XCD
  int by = xcd * 4 + (j & 3);  // 4 m-tiles of 64 per XCD
  int bx = j >> 2;             // 8 n-tiles of 128; advances every 4 blocks
  int m0 = by * 64, n0 = bx * 128;
  int wr = w >> 2, wc = w & 3;  // 2m x 4n waves, wave tile 32x32
  int h = l >> 4, c16 = l & 15;
  int s8 = c16 & 7;

  const char* gA = (const char*)Acat + (size_t)(m0 + (t >> 3)) * (KA * 2) +
                   (t & 7) * 16;
  const char* gB = (const char*)Bcat + (size_t)(n0 + (t >> 3)) * (KB * 2) +
                   (t & 7) * 16;

#define AOFF(mi, wk) \
  ((wr * 32 + (mi)*16 + c16) * 64 + ((((wk)*4 + h) ^ s8) * 8))
#define BOFF(nj, wk) \
  ((wc * 32 + (nj)*16 + c16) * 64 + ((((wk)*4 + h) ^ s8) * 8))

  f32x4 acc[2][2] = {};

  // per-step operand segment offsets (bytes): seg = 1024 ushorts = 2048 B
#define STAGE3(bufi, itv)                                                 \
  {                                                                       \
    size_t aoff = (size_t)(((itv)&15) * 128) + (((itv) >= 32) ? 2048 : 0);\
    size_t boff = (size_t)(((itv)&15) * 128) +                            \
                  (((((itv) >> 4) == 1)) ? 2048 : 0);                     \
    GLOAD16(gA + aoff, (char*)&Alds[bufi][0] + t * 16);                   \
    GLOAD16(gB + boff, (char*)&Blds[bufi][0] + t * 16);                   \
    GLOAD16(gB + (size_t)64 * (KB * 2) + boff,                            \
            (char*)&Blds[bufi][0] + 8192 + t * 16);                       \
  }

#define COMPUTE(bufi)                                                          \
  {                                                                            \
    const unsigned short* Ab = &Alds[bufi][0];                                 \
    const unsigned short* Bb = &Blds[bufi][0];                                 \
    _Pragma("unroll") for (int wk = 0; wk < 2; ++wk) {                         \
      bf16x8 af0 = *(const bf16x8*)(Ab + AOFF(0, wk));                         \
      bf16x8 af1 = *(const bf16x8*)(Ab + AOFF(1, wk));                         \
      bf16x8 bf0 = *(const bf16x8*)(Bb + BOFF(0, wk));                         \
      bf16x8 bf1 = *(const bf16x8*)(Bb + BOFF(1, wk));                         \
      acc[0][0] = __builtin_amdgcn_mfma_f32_16x16x32_bf16(af0, bf0, acc[0][0], 0, 0, 0); \
      acc[0][1] = __builtin_amdgcn_mfma_f32_16x16x32_bf16(af0, bf1, acc[0][1], 0, 0, 0); \
      acc[1][0] = __builtin_amdgcn_mfma_f32_16x16x32_bf16(af1, bf0, acc[1][0], 0, 0, 0); \
      acc[1][1] = __builtin_amdgcn_mfma_f32_16x16x32_bf16(af1, bf1, acc[1][1], 0, 0, 0); \
    }                                                                          \
  }

  const int NT = 48;  // 3 products x 16 K-steps
  STAGE3(0, 0);
  STAGE3(1, 1);
  int cur = 0;
  for (int it = 0; it < NT - 1; ++it) {
    // own stage-it (3 loads) landed when <=3 outstanding (stage it+1 only)
    asm volatile("s_waitcnt vmcnt(3)" ::: "memory");
    __builtin_amdgcn_s_barrier();
    __builtin_amdgcn_sched_barrier(0);
    COMPUTE(cur);
    if (it < NT - 2) {
      int bs = cur + 2;
      if (bs >= 3) bs -= 3;
      STAGE3(bs, it + 2);  // issued after barrier: WAR-safe
    }
    cur = (cur == 2) ? 0 : cur + 1;
  }
  asm volatile("s_waitcnt vmcnt(0)" ::: "memory");
  __builtin_amdgcn_s_barrier();
  __builtin_amdgcn_sched_barrier(0);
  COMPUTE(cur);

  // C/D: col = lane&15, row = (lane>>4)*4 + reg
#pragma unroll
  for (int mi = 0; mi < 2; ++mi)
#pragma unroll
    for (int nj = 0; nj < 2; ++nj) {
      int rb = m0 + wr * 32 + mi * 16 + h * 4;
      int col = n0 + wc * 32 + nj * 16 + c16;
      out[(size_t)(rb + 0) * N_DIM + col] = acc[mi][nj][0];
      out[(size_t)(rb + 1) * N_DIM + col] = acc[mi][nj][1];
      out[(size_t)(rb + 2) * N_DIM + col] = acc[mi][nj][2];
      out[(size_t)(rb + 3) * N_DIM + col] = acc[mi][nj][3];
    }
#undef COMPUTE
#undef STAGE3
#undef AOFF
#undef BOFF
}

// ---------------------------------------------------------------------------
// Launch: 3 kernels.
// ---------------------------------------------------------------------------
extern "C" void kernel_launch(void* const* d_in, const int* in_sizes, int n_in,
                              void* d_out, int out_size, void* d_ws,
                              size_t ws_size, hipStream_t stream) {
  const float* x = (const float*)d_in[0];    // (C, N)
  const float* W = (const float*)d_in[1];    // (O, C)
  const float* eps = (const float*)d_in[2];  // (C, N)
  float* out = (float*)d_out;                // (O, N)
  char* ws = (char*)d_ws;

  double* s_d = (double*)(ws + 0);                          //   8 KB
  float* xT = (float*)(ws + 532480);                        //   4 MB
  float* gT = (float*)(ws + 4726784);                       //   4 MB
  float* partials = (float*)(ws + 8921088);                 //  16 MB (NZ=4)
  unsigned short* Acat = (unsigned short*)(ws + 42475520);  //   8 MB
  unsigned short* Bcat = (unsigned short*)(ws + 55058432);  //   4 MB

  // 1: dist GEMM (first in grid) + transpose + conv_w + norms
  prep_dist_kernel<<<2608, 256, 0, stream>>>(x, eps, W, xT, gT, Acat, s_d,
                                             partials);
  // 2: top-20 + gather + Bcat build
  topk_gather_kernel<<<1024, 128, 0, stream>>>(partials, s_d, xT, gT, Bcat);
  // 3: out = W @ h via bf16 MFMA
  mfma_gemm<<<256, 512, 0, stream>>>(Acat, Bcat, out);
}